// Round 2
// baseline (1057.119 us; speedup 1.0000x reference)
//
#include <hip/hip_runtime.h>
#include <hip/hip_cooperative_groups.h>
#include <math.h>

namespace cg = cooperative_groups;

#define MM 100     // mentions
#define CC 30      // candidates
#define DE 300     // embedding dim
#define NK 3       // relation types
#define NLOOP 10   // LBP iterations
#define INV_SQRT_D 0.05773502691896258f   // 1/sqrt(300)

// ws layout (floats):
//  f      [MM*DE]            @ 0
//  g      [MM*DE]            @ 30000
//  psi    [MM*CC]            @ 60000
//  t      [NK*MM*DE]         @ 63000
//  a      [MM*MM*NK]         @ 153000
//  RE     [NK*MM*CC*DE]      @ 183000       RE[k,i,p,d]
//  phi    [MM*MM*CC*CC]      @ 2883000      [i][j][p][q]
//  mbarA  [MM*MM*CC]         @ 11883000
//  mbarB  [MM*MM*CC]         @ 12183000

// ---------- f = tanh(fmc_in @ W + b) ----------
__global__ __launch_bounds__(256) void k_f(const float* __restrict__ fmc,
                                           const float* __restrict__ W,
                                           const float* __restrict__ b,
                                           float* __restrict__ f) {
  __shared__ float xs[3*DE];
  int m = blockIdx.x;
  for (int e = threadIdx.x; e < 3*DE; e += 256) xs[e] = fmc[m*3*DE + e];
  __syncthreads();
  for (int d = threadIdx.x; d < DE; d += 256) {
    float acc = b[d];
    for (int e = 0; e < 3*DE; ++e) acc = fmaf(xs[e], W[e*DE + d], acc);
    f[m*DE + d] = tanhf(acc);
  }
}

// ---------- g[m,d] = sum_e B[d,e] f[m,e] ----------
__global__ __launch_bounds__(256) void k_g(const float* __restrict__ Bm,
                                           const float* __restrict__ f,
                                           float* __restrict__ g) {
  __shared__ float fs[DE];
  int m = blockIdx.x;
  for (int e = threadIdx.x; e < DE; e += 256) fs[e] = f[m*DE + e];
  __syncthreads();
  for (int d = threadIdx.x; d < DE; d += 256) {
    float acc = 0.f;
    const float* Br = Bm + d*DE;
    for (int e = 0; e < DE; ++e) acc = fmaf(Br[e], fs[e], acc);
    g[m*DE + d] = acc;
  }
}

// ---------- psi[m,c] = ent[m,c,:] . g[m,:] ----------
__global__ __launch_bounds__(256) void k_psi(const float* __restrict__ ent,
                                             const float* __restrict__ g,
                                             float* __restrict__ psi) {
  __shared__ float gs[DE];
  int m = blockIdx.x;
  for (int e = threadIdx.x; e < DE; e += 256) gs[e] = g[m*DE + e];
  __syncthreads();
  int wave = threadIdx.x >> 6, lane = threadIdx.x & 63;
  for (int c = wave; c < CC; c += 4) {
    float acc = 0.f;
    const float* er = ent + (m*CC + c)*DE;
    for (int d = lane; d < DE; d += 64) acc = fmaf(er[d], gs[d], acc);
    #pragma unroll
    for (int off = 32; off; off >>= 1) acc += __shfl_down(acc, off, 64);
    if (lane == 0) psi[m*CC + c] = acc;
  }
}

// ---------- t[k,j,d] = sum_e D[k,d,e] f[j,e] ----------
__global__ __launch_bounds__(256) void k_t(const float* __restrict__ Dm,
                                           const float* __restrict__ f,
                                           float* __restrict__ t) {
  __shared__ float fs[DE];
  int k = blockIdx.x / MM, j = blockIdx.x % MM;
  for (int e = threadIdx.x; e < DE; e += 256) fs[e] = f[j*DE + e];
  __syncthreads();
  for (int d = threadIdx.x; d < DE; d += 256) {
    float acc = 0.f;
    const float* Dr = Dm + (k*DE + d)*DE;
    for (int e = 0; e < DE; ++e) acc = fmaf(Dr[e], fs[e], acc);
    t[(k*MM + j)*DE + d] = acc;
  }
}

// ---------- a[i,j,k] = softmax_k( f_i . t[k,j,:] / sqrt(D) ) ----------
__global__ __launch_bounds__(256) void k_a(const float* __restrict__ f,
                                           const float* __restrict__ t,
                                           float* __restrict__ a) {
  __shared__ float fs[DE];
  int i = blockIdx.x;
  for (int e = threadIdx.x; e < DE; e += 256) fs[e] = f[i*DE + e];
  __syncthreads();
  int wave = threadIdx.x >> 6, lane = threadIdx.x & 63;
  for (int j = wave; j < MM; j += 4) {
    float sk[NK];
    #pragma unroll
    for (int k = 0; k < NK; ++k) {
      float acc = 0.f;
      const float* tr = t + (k*MM + j)*DE;
      for (int d = lane; d < DE; d += 64) acc = fmaf(fs[d], tr[d], acc);
      #pragma unroll
      for (int off = 32; off; off >>= 1) acc += __shfl_down(acc, off, 64);
      sk[k] = acc;
    }
    if (lane == 0) {
      float s0 = sk[0]*INV_SQRT_D, s1 = sk[1]*INV_SQRT_D, s2 = sk[2]*INV_SQRT_D;
      float mx = fmaxf(s0, fmaxf(s1, s2));
      float e0 = expf(s0 - mx), e1 = expf(s1 - mx), e2 = expf(s2 - mx);
      float inv = 1.f / (e0 + e1 + e2);
      float* ar = a + (i*MM + j)*NK;
      ar[0] = e0*inv; ar[1] = e1*inv; ar[2] = e2*inv;
    }
  }
}

// ---------- RE[k] = ent_flat[3000,300] @ R_k[300,300]^T  (tiled NT GEMM) ----------
// block tile 128 rows x 64 cols, BK=20, 256 threads, thread tile 8x4 (interleaved)
__global__ __launch_bounds__(256) void k_re(const float* __restrict__ R,
                                            const float* __restrict__ ent,
                                            float* __restrict__ RE) {
  __shared__ float4 As4[128*5];   // [row][5 float4]  (stride 20 floats)
  __shared__ float4 Bs4[64*5];    // [col][5 float4]
  float* As = (float*)As4;
  float* Bs = (float*)Bs4;

  const int k  = blockIdx.z;
  const int r0 = blockIdx.y * 128;   // row tile (i*CC+p)
  const int d0 = blockIdx.x * 64;    // col tile (d)
  const int tx = threadIdx.x & 15;
  const int ty = threadIdx.x >> 4;
  const float* A  = ent;                  // [3000][300]
  const float* Bk = R + k*DE*DE;          // [300][300]

  float acc[8][4];
  #pragma unroll
  for (int r = 0; r < 8; ++r)
    #pragma unroll
    for (int s = 0; s < 4; ++s) acc[r][s] = 0.f;

  for (int e0 = 0; e0 < DE; e0 += 20) {
    // stage A tile: 128x20 = 2560 elems
    #pragma unroll
    for (int it = 0; it < 10; ++it) {
      int idx = threadIdx.x + it*256;
      int row = idx / 20, e = idx % 20;
      int gr = r0 + row;
      As[idx] = (gr < MM*CC) ? A[gr*DE + e0 + e] : 0.f;
    }
    // stage B tile: 64x20 = 1280 elems
    #pragma unroll
    for (int it = 0; it < 5; ++it) {
      int idx = threadIdx.x + it*256;
      int row = idx / 20, e = idx % 20;
      int gd = d0 + row;
      Bs[idx] = (gd < DE) ? Bk[gd*DE + e0 + e] : 0.f;
    }
    __syncthreads();

    #pragma unroll
    for (int v = 0; v < 5; ++v) {
      float4 av[8], bv[4];
      #pragma unroll
      for (int r = 0; r < 8; ++r) av[r] = As4[(ty + 16*r)*5 + v];
      #pragma unroll
      for (int s = 0; s < 4; ++s) bv[s] = Bs4[(tx + 16*s)*5 + v];
      #pragma unroll
      for (int r = 0; r < 8; ++r)
        #pragma unroll
        for (int s = 0; s < 4; ++s) {
          acc[r][s] = fmaf(av[r].x, bv[s].x, acc[r][s]);
          acc[r][s] = fmaf(av[r].y, bv[s].y, acc[r][s]);
          acc[r][s] = fmaf(av[r].z, bv[s].z, acc[r][s]);
          acc[r][s] = fmaf(av[r].w, bv[s].w, acc[r][s]);
        }
    }
    __syncthreads();
  }

  float* Ck = RE + (size_t)k*MM*CC*DE;
  #pragma unroll
  for (int r = 0; r < 8; ++r) {
    int gr = r0 + ty + 16*r;
    if (gr < MM*CC) {
      #pragma unroll
      for (int s = 0; s < 4; ++s) {
        int gd = d0 + tx + 16*s;
        if (gd < DE) Ck[gr*DE + gd] = acc[r][s];
      }
    }
  }
}

// ---------- phi[i,j,p,q] = sum_d G[p,d]*ent[j,q,d],  G = sum_k a_k RE_k ----------
__global__ __launch_bounds__(64) void k_phi(const float* __restrict__ a,
                                            const float* __restrict__ RE,
                                            const float* __restrict__ ent,
                                            float* __restrict__ phi) {
  __shared__ float Gs[32*DE];
  int i = blockIdx.x / MM, j = blockIdx.x % MM;
  float a0 = a[(i*MM + j)*NK + 0];
  float a1 = a[(i*MM + j)*NK + 1];
  float a2 = a[(i*MM + j)*NK + 2];
  const float4* RE0 = (const float4*)(RE + (0*MM + i)*CC*DE);
  const float4* RE1 = (const float4*)(RE + (1*MM + i)*CC*DE);
  const float4* RE2 = (const float4*)(RE + (2*MM + i)*CC*DE);
  float4* Gs4 = (float4*)Gs;
  for (int idx = threadIdx.x; idx < CC*DE/4; idx += 64) {
    float4 r0 = RE0[idx], r1 = RE1[idx], r2 = RE2[idx];
    float4 gv;
    gv.x = a0*r0.x + a1*r1.x + a2*r2.x;
    gv.y = a0*r0.y + a1*r1.y + a2*r2.y;
    gv.z = a0*r0.z + a1*r1.z + a2*r2.z;
    gv.w = a0*r0.w + a1*r1.w + a2*r2.w;
    Gs4[idx] = gv;
  }
  __syncthreads();

  int tp = threadIdx.x >> 3;
  int tq = threadIdx.x & 7;
  const float4* entj = (const float4*)(ent + j*CC*DE);

  float acc[4][4];
  #pragma unroll
  for (int r = 0; r < 4; ++r)
    #pragma unroll
    for (int s = 0; s < 4; ++s) acc[r][s] = 0.f;

  int qrow[4], prow[4];
  #pragma unroll
  for (int s = 0; s < 4; ++s) {
    int q = tq + 8*s;
    qrow[s] = (q < CC ? q : CC-1) * (DE/4);
  }
  #pragma unroll
  for (int r = 0; r < 4; ++r) prow[r] = (tp + 8*r) * (DE/4);

  float4 ecur[4], enxt[4];
  #pragma unroll
  for (int s = 0; s < 4; ++s) ecur[s] = entj[qrow[s]];

  for (int c = 0; c < DE/4; ++c) {
    if (c + 1 < DE/4) {
      #pragma unroll
      for (int s = 0; s < 4; ++s) enxt[s] = entj[qrow[s] + c + 1];
    }
    float4 g[4];
    #pragma unroll
    for (int r = 0; r < 4; ++r) g[r] = Gs4[prow[r] + c];
    #pragma unroll
    for (int r = 0; r < 4; ++r)
      #pragma unroll
      for (int s = 0; s < 4; ++s) {
        acc[r][s] = fmaf(g[r].x, ecur[s].x, acc[r][s]);
        acc[r][s] = fmaf(g[r].y, ecur[s].y, acc[r][s]);
        acc[r][s] = fmaf(g[r].z, ecur[s].z, acc[r][s]);
        acc[r][s] = fmaf(g[r].w, ecur[s].w, acc[r][s]);
      }
    #pragma unroll
    for (int s = 0; s < 4; ++s) ecur[s] = enxt[s];
  }

  float* ph = phi + (i*MM + j)*CC*CC;
  #pragma unroll
  for (int r = 0; r < 4; ++r) {
    int p = tp + 8*r;
    if (p < CC) {
      #pragma unroll
      for (int s = 0; s < 4; ++s) {
        int q = tq + 8*s;
        if (q < CC) ph[p*CC + q] = acc[r][s];
      }
    }
  }
}

// ---------- zero ----------
__global__ void k_zero(float* __restrict__ p, int n) {
  int idx = blockIdx.x*256 + threadIdx.x;
  if (idx < n) p[idx] = 0.f;
}

// ---------- fused LBP loop (cooperative): 10 iterations + final softmax ----------
// grid = MM blocks (one per i), 256 threads (4 waves; wave w handles j = w,w+4,...)
__global__ __launch_bounds__(256) void k_lbp(const float* __restrict__ phi,
                                             const float* __restrict__ psi,
                                             float* __restrict__ mbA,
                                             float* __restrict__ mbB,
                                             float* __restrict__ out) {
  cg::grid_group grid = cg::this_grid();
  const int i    = blockIdx.x;
  const int wave = threadIdx.x >> 6;
  const int lane = threadIdx.x & 63;

  __shared__ float part[4][32];   // per-wave partial stot
  __shared__ float stot_s[32];
  __shared__ float psi_s[32];
  __shared__ float csw[4][32];    // per-wave cs buffer

  if (threadIdx.x < CC) psi_s[threadIdx.x] = psi[i*CC + threadIdx.x];

  float* cur = mbA;
  float* nxt = mbB;

  for (int it = 0; it < NLOOP; ++it) {
    // ---- stot[i,p] = sum_j cur[j,i,p], 4-wave partials over j ----
    float ps = 0.f;
    if (lane < CC) {
      for (int j = wave*25; j < wave*25 + 25; ++j)
        ps += cur[(j*MM + i)*CC + lane];
      part[wave][lane] = ps;
    }
    __syncthreads();
    if (threadIdx.x < CC)
      stot_s[threadIdx.x] = part[0][threadIdx.x] + part[1][threadIdx.x]
                          + part[2][threadIdx.x] + part[3][threadIdx.x];
    __syncthreads();

    // ---- update mb_new[i,j,:] for j = wave, wave+4, ... ----
    for (int j = wave; j < MM; j += 4) {
      if (lane < CC)
        csw[wave][lane] = psi_s[lane] + stot_s[lane] - cur[(j*MM + i)*CC + lane];
      float x = -1e30f;
      if (lane < CC) {
        const float* ph = phi + (i*MM + j)*CC*CC;
        float mv = -1e30f;
        #pragma unroll
        for (int p = 0; p < CC; ++p) mv = fmaxf(mv, ph[p*CC + lane] + csw[wave][p]);
        x = fmaxf(mv, 0.f);
      }
      float mx = x;
      #pragma unroll
      for (int off = 16; off; off >>= 1) mx = fmaxf(mx, __shfl_xor(mx, off, 32));
      float e = (lane < CC) ? expf(x - mx) : 0.f;
      float se = e;
      #pragma unroll
      for (int off = 16; off; off >>= 1) se += __shfl_xor(se, off, 32);
      if (lane < CC) {
        float sm = e / se;
        float old = cur[(i*MM + j)*CC + lane];
        nxt[(i*MM + j)*CC + lane] = logf(0.5f*expf(old) + 0.5f*sm);
      }
    }
    grid.sync();
    float* tmp = cur; cur = nxt; nxt = tmp;
  }

  // ---- final: out[i,:] = softmax(psi + sum_j cur[j,i,:] - cur[i,i,:]) ----
  {
    float ps = 0.f;
    if (lane < CC) {
      for (int j = wave*25; j < wave*25 + 25; ++j)
        ps += cur[(j*MM + i)*CC + lane];
      part[wave][lane] = ps;
    }
    __syncthreads();
    if (wave == 0 && lane < 32) {
      float x = -1e30f;
      if (lane < CC) {
        float s = part[0][lane] + part[1][lane] + part[2][lane] + part[3][lane];
        s -= cur[(i*MM + i)*CC + lane];
        x = psi_s[lane] + s;
      }
      float mx = x;
      #pragma unroll
      for (int off = 16; off; off >>= 1) mx = fmaxf(mx, __shfl_xor(mx, off, 32));
      float e = (lane < CC) ? expf(x - mx) : 0.f;
      float se = e;
      #pragma unroll
      for (int off = 16; off; off >>= 1) se += __shfl_xor(se, off, 32);
      if (lane < CC) out[i*CC + lane] = e / se;
    }
  }
}

extern "C" void kernel_launch(void* const* d_in, const int* in_sizes, int n_in,
                              void* d_out, int out_size, void* d_ws, size_t ws_size,
                              hipStream_t stream) {
  (void)in_sizes; (void)n_in; (void)out_size; (void)ws_size;
  const float* ent  = (const float*)d_in[0];
  const float* fmc  = (const float*)d_in[1];
  const float* W    = (const float*)d_in[2];
  const float* b    = (const float*)d_in[3];
  const float* Bm   = (const float*)d_in[4];
  const float* R    = (const float*)d_in[5];
  const float* Dm   = (const float*)d_in[6];
  float* out = (float*)d_out;
  float* ws  = (float*)d_ws;

  float* f    = ws + 0;
  float* g    = ws + 30000;
  float* psi  = ws + 60000;
  float* t    = ws + 63000;
  float* a    = ws + 153000;
  float* RE   = ws + 183000;
  float* phi  = ws + 2883000;
  float* mbA  = ws + 11883000;
  float* mbB  = ws + 12183000;

  k_zero<<<(MM*MM*CC + 255)/256, 256, 0, stream>>>(mbA, MM*MM*CC);
  k_f  <<<MM, 256, 0, stream>>>(fmc, W, b, f);
  k_g  <<<MM, 256, 0, stream>>>(Bm, f, g);
  k_psi<<<MM, 256, 0, stream>>>(ent, g, psi);
  k_t  <<<NK*MM, 256, 0, stream>>>(Dm, f, t);
  k_a  <<<MM, 256, 0, stream>>>(f, t, a);
  {
    dim3 grid(5, 24, 3);   // col-tiles(d), row-tiles(i*CC+p), k
    k_re<<<grid, 256, 0, stream>>>(R, ent, RE);
  }
  k_phi<<<MM*MM, 64, 0, stream>>>(a, RE, ent, phi);

  {
    void* args[] = {(void*)&phi, (void*)&psi, (void*)&mbA, (void*)&mbB, (void*)&out};
    hipLaunchCooperativeKernel((void*)k_lbp, dim3(MM), dim3(256), args, 0, stream);
  }
}

// Round 4
// 723.176 us; speedup vs baseline: 1.4618x; 1.4618x over previous
//
#include <hip/hip_runtime.h>
#include <math.h>

#define MM 100     // mentions
#define CC 30      // candidates
#define DE 300     // embedding dim
#define NK 3       // relation types
#define NLOOP 10   // LBP iterations
#define INV_SQRT_D 0.05773502691896258f   // 1/sqrt(300)

// ws layout (floats):
//  f      [MM*DE]            @ 0
//  g      [MM*DE]            @ 30000
//  psi    [MM*CC]            @ 60000
//  t      [NK*MM*DE]         @ 63000
//  a      [MM*MM*NK]         @ 153000
//  RE     [NK*MM*CC*DE]      @ 183000       RE[k,i,p,d]
//  phi    [MM*MM*CC*CC]      @ 2883000      [i][j][p][q]
//  mbarA  [MM*MM*CC]         @ 11883000
//  mbarB  [MM*MM*CC]         @ 12183000
//  stot   [MM*CC]            @ 12483000

// ---------- f = tanh(fmc_in @ W + b) ----------
__global__ __launch_bounds__(256) void k_f(const float* __restrict__ fmc,
                                           const float* __restrict__ W,
                                           const float* __restrict__ b,
                                           float* __restrict__ f) {
  __shared__ float xs[3*DE];
  int m = blockIdx.x;
  for (int e = threadIdx.x; e < 3*DE; e += 256) xs[e] = fmc[m*3*DE + e];
  __syncthreads();
  for (int d = threadIdx.x; d < DE; d += 256) {
    float acc = b[d];
    for (int e = 0; e < 3*DE; ++e) acc = fmaf(xs[e], W[e*DE + d], acc);
    f[m*DE + d] = tanhf(acc);
  }
}

// ---------- g[m,d] = sum_e B[d,e] f[m,e] ----------
__global__ __launch_bounds__(256) void k_g(const float* __restrict__ Bm,
                                           const float* __restrict__ f,
                                           float* __restrict__ g) {
  __shared__ float fs[DE];
  int m = blockIdx.x;
  for (int e = threadIdx.x; e < DE; e += 256) fs[e] = f[m*DE + e];
  __syncthreads();
  for (int d = threadIdx.x; d < DE; d += 256) {
    float acc = 0.f;
    const float* Br = Bm + d*DE;
    for (int e = 0; e < DE; ++e) acc = fmaf(Br[e], fs[e], acc);
    g[m*DE + d] = acc;
  }
}

// ---------- psi[m,c] = ent[m,c,:] . g[m,:] ----------
__global__ __launch_bounds__(256) void k_psi(const float* __restrict__ ent,
                                             const float* __restrict__ g,
                                             float* __restrict__ psi) {
  __shared__ float gs[DE];
  int m = blockIdx.x;
  for (int e = threadIdx.x; e < DE; e += 256) gs[e] = g[m*DE + e];
  __syncthreads();
  int wave = threadIdx.x >> 6, lane = threadIdx.x & 63;
  for (int c = wave; c < CC; c += 4) {
    float acc = 0.f;
    const float* er = ent + (m*CC + c)*DE;
    for (int d = lane; d < DE; d += 64) acc = fmaf(er[d], gs[d], acc);
    #pragma unroll
    for (int off = 32; off; off >>= 1) acc += __shfl_down(acc, off, 64);
    if (lane == 0) psi[m*CC + c] = acc;
  }
}

// ---------- t[k,j,d] = sum_e D[k,d,e] f[j,e] ----------
__global__ __launch_bounds__(256) void k_t(const float* __restrict__ Dm,
                                           const float* __restrict__ f,
                                           float* __restrict__ t) {
  __shared__ float fs[DE];
  int k = blockIdx.x / MM, j = blockIdx.x % MM;
  for (int e = threadIdx.x; e < DE; e += 256) fs[e] = f[j*DE + e];
  __syncthreads();
  for (int d = threadIdx.x; d < DE; d += 256) {
    float acc = 0.f;
    const float* Dr = Dm + (k*DE + d)*DE;
    for (int e = 0; e < DE; ++e) acc = fmaf(Dr[e], fs[e], acc);
    t[(k*MM + j)*DE + d] = acc;
  }
}

// ---------- a[i,j,k] = softmax_k( f_i . t[k,j,:] / sqrt(D) ) ----------
__global__ __launch_bounds__(256) void k_a(const float* __restrict__ f,
                                           const float* __restrict__ t,
                                           float* __restrict__ a) {
  __shared__ float fs[DE];
  int i = blockIdx.x;
  for (int e = threadIdx.x; e < DE; e += 256) fs[e] = f[i*DE + e];
  __syncthreads();
  int wave = threadIdx.x >> 6, lane = threadIdx.x & 63;
  for (int j = wave; j < MM; j += 4) {
    float sk[NK];
    #pragma unroll
    for (int k = 0; k < NK; ++k) {
      float acc = 0.f;
      const float* tr = t + (k*MM + j)*DE;
      for (int d = lane; d < DE; d += 64) acc = fmaf(fs[d], tr[d], acc);
      #pragma unroll
      for (int off = 32; off; off >>= 1) acc += __shfl_down(acc, off, 64);
      sk[k] = acc;
    }
    if (lane == 0) {
      float s0 = sk[0]*INV_SQRT_D, s1 = sk[1]*INV_SQRT_D, s2 = sk[2]*INV_SQRT_D;
      float mx = fmaxf(s0, fmaxf(s1, s2));
      float e0 = expf(s0 - mx), e1 = expf(s1 - mx), e2 = expf(s2 - mx);
      float inv = 1.f / (e0 + e1 + e2);
      float* ar = a + (i*MM + j)*NK;
      ar[0] = e0*inv; ar[1] = e1*inv; ar[2] = e2*inv;
    }
  }
}

// ---------- RE[k] = ent_flat[3000,300] @ R_k[300,300]^T  (tiled NT GEMM) ----------
__global__ __launch_bounds__(256) void k_re(const float* __restrict__ R,
                                            const float* __restrict__ ent,
                                            float* __restrict__ RE) {
  __shared__ float4 As4[128*5];
  __shared__ float4 Bs4[64*5];
  float* As = (float*)As4;
  float* Bs = (float*)Bs4;

  const int k  = blockIdx.z;
  const int r0 = blockIdx.y * 128;
  const int d0 = blockIdx.x * 64;
  const int tx = threadIdx.x & 15;
  const int ty = threadIdx.x >> 4;
  const float* A  = ent;
  const float* Bk = R + k*DE*DE;

  float acc[8][4];
  #pragma unroll
  for (int r = 0; r < 8; ++r)
    #pragma unroll
    for (int s = 0; s < 4; ++s) acc[r][s] = 0.f;

  for (int e0 = 0; e0 < DE; e0 += 20) {
    #pragma unroll
    for (int it = 0; it < 10; ++it) {
      int idx = threadIdx.x + it*256;
      int row = idx / 20, e = idx % 20;
      int gr = r0 + row;
      As[idx] = (gr < MM*CC) ? A[gr*DE + e0 + e] : 0.f;
    }
    #pragma unroll
    for (int it = 0; it < 5; ++it) {
      int idx = threadIdx.x + it*256;
      int row = idx / 20, e = idx % 20;
      int gd = d0 + row;
      Bs[idx] = (gd < DE) ? Bk[gd*DE + e0 + e] : 0.f;
    }
    __syncthreads();

    #pragma unroll
    for (int v = 0; v < 5; ++v) {
      float4 av[8], bv[4];
      #pragma unroll
      for (int r = 0; r < 8; ++r) av[r] = As4[(ty + 16*r)*5 + v];
      #pragma unroll
      for (int s = 0; s < 4; ++s) bv[s] = Bs4[(tx + 16*s)*5 + v];
      #pragma unroll
      for (int r = 0; r < 8; ++r)
        #pragma unroll
        for (int s = 0; s < 4; ++s) {
          acc[r][s] = fmaf(av[r].x, bv[s].x, acc[r][s]);
          acc[r][s] = fmaf(av[r].y, bv[s].y, acc[r][s]);
          acc[r][s] = fmaf(av[r].z, bv[s].z, acc[r][s]);
          acc[r][s] = fmaf(av[r].w, bv[s].w, acc[r][s]);
        }
    }
    __syncthreads();
  }

  float* Ck = RE + (size_t)k*MM*CC*DE;
  #pragma unroll
  for (int r = 0; r < 8; ++r) {
    int gr = r0 + ty + 16*r;
    if (gr < MM*CC) {
      #pragma unroll
      for (int s = 0; s < 4; ++s) {
        int gd = d0 + tx + 16*s;
        if (gd < DE) Ck[gr*DE + gd] = acc[r][s];
      }
    }
  }
}

// ---------- phi[i,j,p,q] = sum_d G[p,d]*ent[j,q,d],  G = sum_k a_k RE_k ----------
// 64-thr block per (i,j). G staged in 4 K-slices of 19 float4 -> 9.1 KB LDS
// -> ~16 blocks/CU -> 4 waves/SIMD (vs 1 in the 36 KB version).
// Single-wave block: LDS ops are in-order per wave, no barriers needed.
__global__ __launch_bounds__(64) void k_phi(const float* __restrict__ a,
                                            const float* __restrict__ RE,
                                            const float* __restrict__ ent,
                                            float* __restrict__ phi) {
  __shared__ float4 Gs4[30*19];   // 9120 B
  int i = blockIdx.x / MM, j = blockIdx.x % MM;
  float a0 = a[(i*MM + j)*NK + 0];
  float a1 = a[(i*MM + j)*NK + 1];
  float a2 = a[(i*MM + j)*NK + 2];
  const float4* RE0 = (const float4*)(RE + (0*MM + i)*CC*DE);
  const float4* RE1 = (const float4*)(RE + (1*MM + i)*CC*DE);
  const float4* RE2 = (const float4*)(RE + (2*MM + i)*CC*DE);

  int tp = threadIdx.x >> 3;   // 0..7
  int tq = threadIdx.x & 7;    // 0..7
  const float4* entj = (const float4*)(ent + j*CC*DE);

  float acc[4][4];
  #pragma unroll
  for (int r = 0; r < 4; ++r)
    #pragma unroll
    for (int s = 0; s < 4; ++s) acc[r][s] = 0.f;

  int qrow[4], prow[4];
  #pragma unroll
  for (int s = 0; s < 4; ++s) {
    int q = tq + 8*s;
    qrow[s] = (q < CC ? q : CC-1) * (DE/4);   // clamp q=30,31 (masked at store)
  }
  #pragma unroll
  for (int r = 0; r < 4; ++r) prow[r] = (tp + 8*r) * 19;   // LDS slice stride

  float4 ecur[4], enxt[4];
  #pragma unroll
  for (int s = 0; s < 4; ++s) ecur[s] = entj[qrow[s]];

  for (int stage = 0; stage < 4; ++stage) {
    const int c0 = stage * 19;
    const int cn = (stage == 3) ? 18 : 19;   // 19+19+19+18 = 75 = DE/4
    // stage G columns [c0, c0+cn): blend 3 RE streams with a_k
    for (int idx = threadIdx.x; idx < 30*cn; idx += 64) {
      int p = idx / cn, v = idx % cn;
      int src = p*(DE/4) + c0 + v;
      float4 r0 = RE0[src], r1 = RE1[src], r2 = RE2[src];
      float4 gv;
      gv.x = a0*r0.x + a1*r1.x + a2*r2.x;
      gv.y = a0*r0.y + a1*r1.y + a2*r2.y;
      gv.z = a0*r0.z + a1*r1.z + a2*r2.z;
      gv.w = a0*r0.w + a1*r1.w + a2*r2.w;
      Gs4[p*19 + v] = gv;
    }
    // compute over this slice
    for (int cc = 0; cc < cn; ++cc) {
      int c = c0 + cc;
      if (c + 1 < DE/4) {
        #pragma unroll
        for (int s = 0; s < 4; ++s) enxt[s] = entj[qrow[s] + c + 1];
      }
      float4 g[4];
      #pragma unroll
      for (int r = 0; r < 4; ++r) g[r] = Gs4[prow[r] + cc];
      #pragma unroll
      for (int r = 0; r < 4; ++r)
        #pragma unroll
        for (int s = 0; s < 4; ++s) {
          acc[r][s] = fmaf(g[r].x, ecur[s].x, acc[r][s]);
          acc[r][s] = fmaf(g[r].y, ecur[s].y, acc[r][s]);
          acc[r][s] = fmaf(g[r].z, ecur[s].z, acc[r][s]);
          acc[r][s] = fmaf(g[r].w, ecur[s].w, acc[r][s]);
        }
      #pragma unroll
      for (int s = 0; s < 4; ++s) ecur[s] = enxt[s];
    }
  }

  float* ph = phi + (i*MM + j)*CC*CC;
  #pragma unroll
  for (int r = 0; r < 4; ++r) {
    int p = tp + 8*r;
    if (p < CC) {
      #pragma unroll
      for (int s = 0; s < 4; ++s) {
        int q = tq + 8*s;
        if (q < CC) ph[p*CC + q] = acc[r][s];
      }
    }
  }
}

// ---------- zero ----------
__global__ void k_zero(float* __restrict__ p, int n) {
  int idx = blockIdx.x*256 + threadIdx.x;
  if (idx < n) p[idx] = 0.f;
}

// ---------- stot[i,p] = sum_j mbar[j,i,p] ----------
__global__ __launch_bounds__(256) void k_st(const float* __restrict__ mb,
                                            float* __restrict__ stot) {
  int idx = blockIdx.x*256 + threadIdx.x;   // idx = i*CC + p
  if (idx < MM*CC) {
    float s = 0.f;
    for (int j = 0; j < MM; ++j) s += mb[j*(MM*CC) + idx];
    stot[idx] = s;
  }
}

// ---------- one damped LBP update, block = (i,j), 1 wave ----------
__global__ __launch_bounds__(64) void k_up(const float* __restrict__ phi,
                                           const float* __restrict__ psi,
                                           const float* __restrict__ stot,
                                           const float* __restrict__ mb_old,
                                           float* __restrict__ mb_new) {
  int i = blockIdx.x / MM, j = blockIdx.x % MM;
  int lane = threadIdx.x;
  __shared__ float cs[CC];
  if (lane < CC)
    cs[lane] = psi[i*CC + lane] + stot[i*CC + lane] - mb_old[(j*MM + i)*CC + lane];
  __syncthreads();
  float x = -1e30f;
  if (lane < CC) {
    const float* ph = phi + (i*MM + j)*CC*CC;
    float mv = -1e30f;
    #pragma unroll
    for (int p = 0; p < CC; ++p) mv = fmaxf(mv, ph[p*CC + lane] + cs[p]);
    x = fmaxf(mv, 0.f);
  }
  float mx = x;
  #pragma unroll
  for (int off = 16; off; off >>= 1) mx = fmaxf(mx, __shfl_xor(mx, off, 32));
  float e = (lane < CC) ? expf(x - mx) : 0.f;
  float se = e;
  #pragma unroll
  for (int off = 16; off; off >>= 1) se += __shfl_xor(se, off, 32);
  if (lane < CC) {
    float sm = e / se;
    float old = mb_old[(i*MM + j)*CC + lane];
    mb_new[(i*MM + j)*CC + lane] = logf(0.5f*expf(old) + 0.5f*sm);
  }
}

// ---------- out[i,:] = softmax( psi + sum_j mbar[j,i,:] - mbar[i,i,:] ) ----------
__global__ __launch_bounds__(64) void k_final(const float* __restrict__ psi,
                                              const float* __restrict__ mb,
                                              float* __restrict__ out) {
  int i = blockIdx.x;
  int lane = threadIdx.x;
  float x = -1e30f;
  if (lane < CC) {
    float s = 0.f;
    for (int j = 0; j < MM; ++j) s += mb[(j*MM + i)*CC + lane];
    s -= mb[(i*MM + i)*CC + lane];
    x = psi[i*CC + lane] + s;
  }
  float mx = x;
  #pragma unroll
  for (int off = 16; off; off >>= 1) mx = fmaxf(mx, __shfl_xor(mx, off, 32));
  float e = (lane < CC) ? expf(x - mx) : 0.f;
  float se = e;
  #pragma unroll
  for (int off = 16; off; off >>= 1) se += __shfl_xor(se, off, 32);
  if (lane < CC) out[i*CC + lane] = e / se;
}

extern "C" void kernel_launch(void* const* d_in, const int* in_sizes, int n_in,
                              void* d_out, int out_size, void* d_ws, size_t ws_size,
                              hipStream_t stream) {
  (void)in_sizes; (void)n_in; (void)out_size; (void)ws_size;
  const float* ent  = (const float*)d_in[0];
  const float* fmc  = (const float*)d_in[1];
  const float* W    = (const float*)d_in[2];
  const float* b    = (const float*)d_in[3];
  const float* Bm   = (const float*)d_in[4];
  const float* R    = (const float*)d_in[5];
  const float* Dm   = (const float*)d_in[6];
  float* out = (float*)d_out;
  float* ws  = (float*)d_ws;

  float* f    = ws + 0;
  float* g    = ws + 30000;
  float* psi  = ws + 60000;
  float* t    = ws + 63000;
  float* a    = ws + 153000;
  float* RE   = ws + 183000;
  float* phi  = ws + 2883000;
  float* mbA  = ws + 11883000;
  float* mbB  = ws + 12183000;
  float* stot = ws + 12483000;

  k_zero<<<(MM*MM*CC + 255)/256, 256, 0, stream>>>(mbA, MM*MM*CC);
  k_f  <<<MM, 256, 0, stream>>>(fmc, W, b, f);
  k_g  <<<MM, 256, 0, stream>>>(Bm, f, g);
  k_psi<<<MM, 256, 0, stream>>>(ent, g, psi);
  k_t  <<<NK*MM, 256, 0, stream>>>(Dm, f, t);
  k_a  <<<MM, 256, 0, stream>>>(f, t, a);
  {
    dim3 grid(5, 24, 3);
    k_re<<<grid, 256, 0, stream>>>(R, ent, RE);
  }
  k_phi<<<MM*MM, 64, 0, stream>>>(a, RE, ent, phi);

  float* cur = mbA; float* nxt = mbB;
  for (int it = 0; it < NLOOP; ++it) {
    k_st<<<(MM*CC + 255)/256, 256, 0, stream>>>(cur, stot);
    k_up<<<MM*MM, 64, 0, stream>>>(phi, psi, stot, cur, nxt);
    float* tmp = cur; cur = nxt; nxt = tmp;
  }
  k_final<<<MM, 64, 0, stream>>>(psi, cur, out);
}